// Round 1
// baseline (2080.222 us; speedup 1.0000x reference)
//
#include <hip/hip_runtime.h>
#include <hip/hip_bf16.h>

#define HID 64
#define FNODE 16
#define FEDGE 8
#define K1 136      // 2*HID + FEDGE
#define N1 128      // 2*HID
#define ZSTRIDE 65  // 64 + 1 pad (bank-conflict-free for both k-major reads and writes)

// ---------------- degree / norm ----------------
__global__ void k_deg_init(float* deg, int N) {
    int n = blockIdx.x * 256 + threadIdx.x;
    if (n < N) deg[n] = 1.0f;  // self-loop
}

__global__ void k_deg_count(const int* __restrict__ ei, float* deg, int E) {
    int e = blockIdx.x * 256 + threadIdx.x;
    if (e < E) atomicAdd(&deg[ei[E + e]], 1.0f);  // dst
}

__global__ void k_dis(float* deg, int N) {  // in-place deg -> 1/sqrt(deg)
    int n = blockIdx.x * 256 + threadIdx.x;
    if (n < N) deg[n] = 1.0f / sqrtf(deg[n]);
}

// ---------------- x @ W1  (K=16) ----------------
__global__ __launch_bounds__(256) void k_xw1(const float* __restrict__ x,
                                             const float* __restrict__ W,
                                             float* __restrict__ xw, int N) {
    int t = blockIdx.x * 256 + threadIdx.x;
    int n = t >> 6, h = t & 63;
    if (n >= N) return;
    float acc = 0.f;
#pragma unroll
    for (int k = 0; k < FNODE; ++k) acc += x[n * FNODE + k] * W[k * HID + h];
    xw[t] = acc;
}

// ---------------- h @ W2  (K=64) ----------------
__global__ __launch_bounds__(256) void k_xw2(const float* __restrict__ h,
                                             const float* __restrict__ W,
                                             float* __restrict__ xw, int N) {
    int t = blockIdx.x * 256 + threadIdx.x;
    int n = t >> 6, hh = t & 63;
    if (n >= N) return;
    float acc = 0.f;
#pragma unroll
    for (int k = 0; k < HID; ++k) acc += h[n * HID + k] * W[k * HID + hh];
    xw[t] = acc;
}

// ---------------- edge scatter: agg[dst] += xw[src]*norm ----------------
__global__ __launch_bounds__(256) void k_scatter(const float* __restrict__ xw,
                                                 const int* __restrict__ ei,
                                                 const float* __restrict__ dis,
                                                 float* __restrict__ agg, int E) {
    int t = blockIdx.x * 256 + threadIdx.x;
    int e = t >> 6, h = t & 63;
    if (e >= E) return;
    int s = ei[e];
    int d = ei[E + e];
    float nrm = dis[s] * dis[d];
    atomicAdd(&agg[d * HID + h], xw[s * HID + h] * nrm);
}

// ---------------- self-loop + bias + relu ----------------
__global__ __launch_bounds__(256) void k_postconv(const float* __restrict__ xw,
                                                  const float* __restrict__ agg,
                                                  const float* __restrict__ dis,
                                                  const float* __restrict__ b,
                                                  float* __restrict__ hout, int N) {
    int t = blockIdx.x * 256 + threadIdx.x;
    int n = t >> 6, h = t & 63;
    if (n >= N) return;
    float di = dis[n];
    hout[t] = fmaxf(agg[t] + xw[t] * di * di + b[h], 0.f);
}

// ---------------- edge MLP: q = mlp([h[src]|h[dst]|ea]) ----------------
// block = 256 threads = 4 waves, 64 edges per block.
__global__ __launch_bounds__(256) void k_edge_mlp(
    const float* __restrict__ h, const int* __restrict__ ei,
    const float* __restrict__ ea,
    const float* __restrict__ mW1, const float* __restrict__ mb1,
    const float* __restrict__ mW2, const float* __restrict__ mb2,
    const float* __restrict__ mW3, const float* __restrict__ mb3,
    float* __restrict__ q, int E) {
    __shared__ float zt[K1 * ZSTRIDE];  // 35.4 KB; reused as z1t[128*65] after layer 1
    __shared__ float qpart[4][64];

    const int tid = threadIdx.x;
    const int lane = tid & 63;
    const int wave = tid >> 6;
    const int m0 = blockIdx.x * 64;

    // ---- stage Z: wave w owns edges m = w*16 .. w*16+15
    for (int i = 0; i < 16; ++i) {
        int m = wave * 16 + i;
        int e = m0 + m;
        bool valid = (e < E);
        int s = valid ? ei[e] : 0;
        int d = valid ? ei[E + e] : 0;
        float hs = h[s * HID + lane];            // coalesced 256B
        float hd = h[d * HID + lane];
        zt[lane * ZSTRIDE + m] = hs;             // banks (lane+m)%32: 2/bank, free
        zt[(HID + lane) * ZSTRIDE + m] = hd;
        if (lane < FEDGE)
            zt[(2 * HID + lane) * ZSTRIDE + m] = valid ? ea[e * FEDGE + lane] : 0.f;
    }
    __syncthreads();

    // ---- layer 1: wave w computes cols [w*32, w*32+32)
    const int j0 = __builtin_amdgcn_readfirstlane(wave * 32);
    float acc[32];
#pragma unroll
    for (int j = 0; j < 32; ++j) acc[j] = mb1[j0 + j];
    for (int k = 0; k < K1; ++k) {
        float a = zt[k * ZSTRIDE + lane];
        const float4* wrow = (const float4*)(mW1 + k * N1 + j0);  // uniform -> s_load
#pragma unroll
        for (int jv = 0; jv < 8; ++jv) {
            float4 wv = wrow[jv];
            acc[jv * 4 + 0] += a * wv.x;
            acc[jv * 4 + 1] += a * wv.y;
            acc[jv * 4 + 2] += a * wv.z;
            acc[jv * 4 + 3] += a * wv.w;
        }
    }
    __syncthreads();  // everyone done reading zt
#pragma unroll
    for (int j = 0; j < 32; ++j)
        zt[(j0 + j) * ZSTRIDE + lane] = fmaxf(acc[j], 0.f);  // z1t[j][m]
    __syncthreads();

    // ---- layer 2: wave w computes cols [w*16, w*16+16)
    const int j2 = __builtin_amdgcn_readfirstlane(wave * 16);
    float acc2[16];
#pragma unroll
    for (int j = 0; j < 16; ++j) acc2[j] = mb2[j2 + j];
    for (int k = 0; k < N1; ++k) {
        float a = zt[k * ZSTRIDE + lane];
        const float4* wrow = (const float4*)(mW2 + k * HID + j2);
#pragma unroll
        for (int jv = 0; jv < 4; ++jv) {
            float4 wv = wrow[jv];
            acc2[jv * 4 + 0] += a * wv.x;
            acc2[jv * 4 + 1] += a * wv.y;
            acc2[jv * 4 + 2] += a * wv.z;
            acc2[jv * 4 + 3] += a * wv.w;
        }
    }

    // ---- layer 3: partial dot with mW3, reduce across waves
    float p = 0.f;
#pragma unroll
    for (int j = 0; j < 16; ++j) p += fmaxf(acc2[j], 0.f) * mW3[j2 + j];
    qpart[wave][lane] = p;
    __syncthreads();
    if (tid < 64) {
        int e = m0 + lane;
        if (e < E)
            q[e] = qpart[0][lane] + qpart[1][lane] + qpart[2][lane] + qpart[3][lane] +
                   mb3[0];
    }
}

extern "C" void kernel_launch(void* const* d_in, const int* in_sizes, int n_in,
                              void* d_out, int out_size, void* d_ws, size_t ws_size,
                              hipStream_t stream) {
    const float* x   = (const float*)d_in[0];
    const int*   ei  = (const int*)d_in[1];
    const float* ea  = (const float*)d_in[2];
    const float* W1  = (const float*)d_in[3];
    const float* b1  = (const float*)d_in[4];
    const float* W2  = (const float*)d_in[5];
    const float* b2  = (const float*)d_in[6];
    const float* mW1 = (const float*)d_in[7];
    const float* mb1 = (const float*)d_in[8];
    const float* mW2 = (const float*)d_in[9];
    const float* mb2 = (const float*)d_in[10];
    const float* mW3 = (const float*)d_in[11];
    const float* mb3 = (const float*)d_in[12];
    float* q = (float*)d_out;

    const int N = in_sizes[0] / FNODE;
    const int E = in_sizes[1] / 2;

    // workspace layout (floats)
    float* dis = (float*)d_ws;                 // N      (deg then 1/sqrt(deg))
    float* A   = dis + ((N + 255) & ~255);     // N*HID  (xw1 / xw2)
    float* B   = A + (size_t)N * HID;          // N*HID  (agg1 / h1)
    float* C   = B + (size_t)N * HID;          // N*HID  (agg2 / h2)

    const int nThreads = 256;
    const int gN   = (N + nThreads - 1) / nThreads;
    const int gNH  = (N * HID + nThreads - 1) / nThreads;
    const int gE   = (E + nThreads - 1) / nThreads;
    const int gEH  = (int)(((long long)E * HID + nThreads - 1) / nThreads);
    const int gMLP = (E + 63) / 64;

    // degree + norm (dis buffer)
    k_deg_init<<<gN, nThreads, 0, stream>>>(dis, N);
    k_deg_count<<<gE, nThreads, 0, stream>>>(ei, dis, E);
    k_dis<<<gN, nThreads, 0, stream>>>(dis, N);

    // conv 1
    k_xw1<<<gNH, nThreads, 0, stream>>>(x, W1, A, N);
    hipMemsetAsync(B, 0, (size_t)N * HID * sizeof(float), stream);
    k_scatter<<<gEH, nThreads, 0, stream>>>(A, ei, dis, B, E);
    k_postconv<<<gNH, nThreads, 0, stream>>>(A, B, dis, b1, B, N);  // h1 in B

    // conv 2
    k_xw2<<<gNH, nThreads, 0, stream>>>(B, W2, A, N);
    hipMemsetAsync(C, 0, (size_t)N * HID * sizeof(float), stream);
    k_scatter<<<gEH, nThreads, 0, stream>>>(A, ei, dis, C, E);
    k_postconv<<<gNH, nThreads, 0, stream>>>(A, C, dis, b2, C, N);  // h2 in C

    // edge MLP
    k_edge_mlp<<<gMLP, nThreads, 0, stream>>>(C, ei, ea, mW1, mb1, mW2, mb2, mW3,
                                              mb3, q, E);
}

// Round 3
// 1339.705 us; speedup vs baseline: 1.5527x; 1.5527x over previous
//
#include <hip/hip_runtime.h>
#include <hip/hip_bf16.h>

#define HID 64
#define FNODE 16
#define FEDGE 8
#define ZSTR 168  // bf16 elems per LDS row: 136 data + zero-pad to 160 + 8 (bank spread)

typedef __bf16 v8bf __attribute__((ext_vector_type(8)));
typedef float v4f __attribute__((ext_vector_type(4)));

// ---------------- packed split-bf16 weight fragments (rewritten every launch) ----
// layer1: K padded 136->160 (5 ktiles), N=128 (8 ntiles): frag f=kt*8+nt, elem f*512+lane*8+j
// layer2: K=128 (4 ktiles), N=64 (4 ntiles):              frag f=kt*4+nt
__device__ __bf16 g_w1h[20480];
__device__ __bf16 g_w1l[20480];
__device__ __bf16 g_w2h[8192];
__device__ __bf16 g_w2l[8192];

__global__ void k_pack(const float* __restrict__ mW1, const float* __restrict__ mW2) {
    int gid = blockIdx.x * 256 + threadIdx.x;
    if (gid < 20480) {
        int j = gid & 7, lane = (gid >> 3) & 63, f = gid >> 9;
        int kt = f >> 3, nt = f & 7;
        int k = kt * 32 + (lane >> 4) * 8 + j;
        int col = nt * 16 + (lane & 15);
        float x = (k < 136) ? mW1[k * 128 + col] : 0.f;
        __bf16 hi = (__bf16)x;
        g_w1h[gid] = hi;
        g_w1l[gid] = (__bf16)(x - (float)hi);
    } else if (gid < 28672) {
        int t = gid - 20480;
        int j = t & 7, lane = (t >> 3) & 63, f = t >> 9;
        int kt = f >> 2, nt = f & 3;
        int k = kt * 32 + (lane >> 4) * 8 + j;
        int col = nt * 16 + (lane & 15);
        float x = mW2[k * 64 + col];
        __bf16 hi = (__bf16)x;
        g_w2h[t] = hi;
        g_w2l[t] = (__bf16)(x - (float)hi);
    }
}

// ---------------- degree / norm ----------------
__global__ void k_deg_init(float* deg, int N) {
    int n = blockIdx.x * 256 + threadIdx.x;
    if (n < N) deg[n] = 1.0f;  // self-loop
}

__global__ void k_deg_count(const int* __restrict__ ei, float* deg, int E) {
    int e = blockIdx.x * 256 + threadIdx.x;
    if (e < E) atomicAdd(&deg[ei[E + e]], 1.0f);  // dst
}

__global__ void k_dis(float* deg, int N) {  // in-place deg -> 1/sqrt(deg)
    int n = blockIdx.x * 256 + threadIdx.x;
    if (n < N) deg[n] = 1.0f / sqrtf(deg[n]);
}

// ---------------- x @ W1  (K=16) ----------------
__global__ __launch_bounds__(256) void k_xw1(const float* __restrict__ x,
                                             const float* __restrict__ W,
                                             float* __restrict__ xw, int N) {
    int t = blockIdx.x * 256 + threadIdx.x;
    int n = t >> 6, h = t & 63;
    if (n >= N) return;
    float acc = 0.f;
#pragma unroll
    for (int k = 0; k < FNODE; ++k) acc += x[n * FNODE + k] * W[k * HID + h];
    xw[t] = acc;
}

// ---------------- h @ W2  (K=64) ----------------
__global__ __launch_bounds__(256) void k_xw2(const float* __restrict__ h,
                                             const float* __restrict__ W,
                                             float* __restrict__ xw, int N) {
    int t = blockIdx.x * 256 + threadIdx.x;
    int n = t >> 6, hh = t & 63;
    if (n >= N) return;
    float acc = 0.f;
#pragma unroll
    for (int k = 0; k < HID; ++k) acc += h[n * HID + k] * W[k * HID + hh];
    xw[t] = acc;
}

// ---------------- edge scatter: agg[dst] += xw[src]*norm ----------------
__global__ __launch_bounds__(256) void k_scatter(const float* __restrict__ xw,
                                                 const int* __restrict__ ei,
                                                 const float* __restrict__ dis,
                                                 float* __restrict__ agg, int E) {
    int t = blockIdx.x * 256 + threadIdx.x;
    int e = t >> 6, h = t & 63;
    if (e >= E) return;
    int s = ei[e];
    int d = ei[E + e];
    float nrm = dis[s] * dis[d];
    atomicAdd(&agg[d * HID + h], xw[s * HID + h] * nrm);
}

// ---------------- self-loop + bias + relu ----------------
__global__ __launch_bounds__(256) void k_postconv(const float* __restrict__ xw,
                                                  const float* __restrict__ agg,
                                                  const float* __restrict__ dis,
                                                  const float* __restrict__ b,
                                                  float* __restrict__ hout, int N) {
    int t = blockIdx.x * 256 + threadIdx.x;
    int n = t >> 6, h = t & 63;
    if (n >= N) return;
    float di = dis[n];
    hout[t] = fmaxf(agg[t] + xw[t] * di * di + b[h], 0.f);
}

// ---------------- split-bf16 helper: 8 floats -> hi/lo v8bf in LDS ----------------
__device__ __forceinline__ void split8(const float* __restrict__ x, __bf16* ph,
                                       __bf16* pl) {
    v8bf hi, lo;
#pragma unroll
    for (int i = 0; i < 8; ++i) {
        float f = x[i];
        __bf16 h = (__bf16)f;
        hi[i] = h;
        lo[i] = (__bf16)(f - (float)h);
    }
    *(v8bf*)ph = hi;
    *(v8bf*)pl = lo;
}

// ---------------- edge MLP via split-bf16 MFMA ----------------
// block = 256 threads (4 waves) = 64 edges. Layer1: M=64,N=128,K=160(pad);
// layer2: M=64,N=64,K=128. Waves split by N-tiles; split-bf16: hh + hl + lh.
__global__ __launch_bounds__(256) void k_edge_mlp(
    const float* __restrict__ h, const int* __restrict__ ei,
    const float* __restrict__ ea,
    const float* __restrict__ mb1, const float* __restrict__ mb2,
    const float* __restrict__ mW3, const float* __restrict__ mb3,
    float* __restrict__ q, int E) {
    __shared__ __align__(16) __bf16 zh[64][ZSTR];
    __shared__ __align__(16) __bf16 zl[64][ZSTR];
    __shared__ float qpart[4][64];

    const int tid = threadIdx.x;
    const int lane = tid & 63;
    const int wave = tid >> 6;
    const int g = lane >> 4;    // 16-lane group
    const int cb = lane & 15;   // row/col base within 16
    const int m0 = blockIdx.x * 64;

    // ---- stage z = [h_src(64) | h_dst(64) | ea(8) | zeros(24)] hi/lo bf16
    {
        const int m = tid >> 2, qt = tid & 3;  // 4 threads per edge
        const int e = m0 + m;
        const bool valid = e < E;
        const int s = valid ? ei[e] : 0;
        const int d = valid ? ei[E + e] : 0;
        float buf[8];
        const float* ps = h + (size_t)s * HID + qt * 16;
        const float* pd = h + (size_t)d * HID + qt * 16;
#pragma unroll
        for (int i = 0; i < 8; ++i) buf[i] = ps[i];
        split8(buf, &zh[m][qt * 16], &zl[m][qt * 16]);
#pragma unroll
        for (int i = 0; i < 8; ++i) buf[i] = ps[8 + i];
        split8(buf, &zh[m][qt * 16 + 8], &zl[m][qt * 16 + 8]);
#pragma unroll
        for (int i = 0; i < 8; ++i) buf[i] = pd[i];
        split8(buf, &zh[m][64 + qt * 16], &zl[m][64 + qt * 16]);
#pragma unroll
        for (int i = 0; i < 8; ++i) buf[i] = pd[8 + i];
        split8(buf, &zh[m][64 + qt * 16 + 8], &zl[m][64 + qt * 16 + 8]);
        if (qt == 0) {
#pragma unroll
            for (int i = 0; i < 8; ++i) buf[i] = valid ? ea[(size_t)e * FEDGE + i] : 0.f;
            split8(buf, &zh[m][128], &zl[m][128]);
            v8bf zz = {};
#pragma unroll
            for (int c = 136; c < 160; c += 8) {
                *(v8bf*)&zh[m][c] = zz;
                *(v8bf*)&zl[m][c] = zz;
            }
        }
    }
    __syncthreads();

    // ---- layer 1: wave owns col-tiles nt0, nt0+1 (32 of 128 cols), all 64 edges
    const int nt0 = wave * 2;
    v4f acc[2][4];
    {
        float b0 = mb1[nt0 * 16 + cb];
        float b1 = mb1[nt0 * 16 + 16 + cb];
#pragma unroll
        for (int mt = 0; mt < 4; ++mt) {
            acc[0][mt] = (v4f){b0, b0, b0, b0};
            acc[1][mt] = (v4f){b1, b1, b1, b1};
        }
    }
    const v8bf* w1h = (const v8bf*)g_w1h;
    const v8bf* w1l = (const v8bf*)g_w1l;
#pragma unroll
    for (int kt = 0; kt < 5; ++kt) {
        v8bf bh0 = w1h[(kt * 8 + nt0) * 64 + lane];
        v8bf bl0 = w1l[(kt * 8 + nt0) * 64 + lane];
        v8bf bh1 = w1h[(kt * 8 + nt0 + 1) * 64 + lane];
        v8bf bl1 = w1l[(kt * 8 + nt0 + 1) * 64 + lane];
#pragma unroll
        for (int mt = 0; mt < 4; ++mt) {
            v8bf ah = *(const v8bf*)&zh[mt * 16 + cb][kt * 32 + g * 8];
            v8bf al = *(const v8bf*)&zl[mt * 16 + cb][kt * 32 + g * 8];
            acc[0][mt] = __builtin_amdgcn_mfma_f32_16x16x32_bf16(ah, bh0, acc[0][mt], 0, 0, 0);
            acc[0][mt] = __builtin_amdgcn_mfma_f32_16x16x32_bf16(ah, bl0, acc[0][mt], 0, 0, 0);
            acc[0][mt] = __builtin_amdgcn_mfma_f32_16x16x32_bf16(al, bh0, acc[0][mt], 0, 0, 0);
            acc[1][mt] = __builtin_amdgcn_mfma_f32_16x16x32_bf16(ah, bh1, acc[1][mt], 0, 0, 0);
            acc[1][mt] = __builtin_amdgcn_mfma_f32_16x16x32_bf16(ah, bl1, acc[1][mt], 0, 0, 0);
            acc[1][mt] = __builtin_amdgcn_mfma_f32_16x16x32_bf16(al, bh1, acc[1][mt], 0, 0, 0);
        }
    }
    __syncthreads();  // everyone done reading z before overwriting with z1

    // ---- write z1 = relu(acc) split into cols [nt0*16, nt0*16+32) of z buffers
    // D layout (m89-verified): col = lane&15, row = (lane>>4)*4 + reg
#pragma unroll
    for (int c = 0; c < 2; ++c)
#pragma unroll
        for (int mt = 0; mt < 4; ++mt)
#pragma unroll
            for (int r = 0; r < 4; ++r) {
                float vv = fmaxf(acc[c][mt][r], 0.f);
                __bf16 hi = (__bf16)vv;
                int row = mt * 16 + g * 4 + r;
                int col = (nt0 + c) * 16 + cb;
                zh[row][col] = hi;
                zl[row][col] = (__bf16)(vv - (float)hi);
            }
    __syncthreads();

    // ---- layer 2: wave owns col-tile nt=wave (16 of 64 cols), all 64 edges
    v4f acc2[4];
    {
        float b = mb2[wave * 16 + cb];
#pragma unroll
        for (int mt = 0; mt < 4; ++mt) acc2[mt] = (v4f){b, b, b, b};
    }
    const v8bf* w2h = (const v8bf*)g_w2h;
    const v8bf* w2l = (const v8bf*)g_w2l;
#pragma unroll
    for (int kt = 0; kt < 4; ++kt) {
        v8bf bh = w2h[(kt * 4 + wave) * 64 + lane];
        v8bf bl = w2l[(kt * 4 + wave) * 64 + lane];
#pragma unroll
        for (int mt = 0; mt < 4; ++mt) {
            v8bf ah = *(const v8bf*)&zh[mt * 16 + cb][kt * 32 + g * 8];
            v8bf al = *(const v8bf*)&zl[mt * 16 + cb][kt * 32 + g * 8];
            acc2[mt] = __builtin_amdgcn_mfma_f32_16x16x32_bf16(ah, bh, acc2[mt], 0, 0, 0);
            acc2[mt] = __builtin_amdgcn_mfma_f32_16x16x32_bf16(ah, bl, acc2[mt], 0, 0, 0);
            acc2[mt] = __builtin_amdgcn_mfma_f32_16x16x32_bf16(al, bh, acc2[mt], 0, 0, 0);
        }
    }

    // ---- layer 3: q = relu(z2) @ mW3 + mb3; reduce 16 cols per wave via shfl,
    // then cross-wave via LDS.
    const float w3 = mW3[wave * 16 + cb];
#pragma unroll
    for (int mt = 0; mt < 4; ++mt) {
#pragma unroll
        for (int r = 0; r < 4; ++r) {
            float pr = fmaxf(acc2[mt][r], 0.f) * w3;
            pr += __shfl_xor(pr, 1, 16);
            pr += __shfl_xor(pr, 2, 16);
            pr += __shfl_xor(pr, 4, 16);
            pr += __shfl_xor(pr, 8, 16);
            if (cb == 0) qpart[wave][mt * 16 + g * 4 + r] = pr;
        }
    }
    __syncthreads();
    if (tid < 64) {
        int e = m0 + tid;
        if (e < E)
            q[e] = qpart[0][tid] + qpart[1][tid] + qpart[2][tid] + qpart[3][tid] +
                   mb3[0];
    }
}

extern "C" void kernel_launch(void* const* d_in, const int* in_sizes, int n_in,
                              void* d_out, int out_size, void* d_ws, size_t ws_size,
                              hipStream_t stream) {
    const float* x   = (const float*)d_in[0];
    const int*   ei  = (const int*)d_in[1];
    const float* ea  = (const float*)d_in[2];
    const float* W1  = (const float*)d_in[3];
    const float* b1  = (const float*)d_in[4];
    const float* W2  = (const float*)d_in[5];
    const float* b2  = (const float*)d_in[6];
    const float* mW1 = (const float*)d_in[7];
    const float* mb1 = (const float*)d_in[8];
    const float* mW2 = (const float*)d_in[9];
    const float* mb2 = (const float*)d_in[10];
    const float* mW3 = (const float*)d_in[11];
    const float* mb3 = (const float*)d_in[12];
    float* q = (float*)d_out;

    const int N = in_sizes[0] / FNODE;
    const int E = in_sizes[1] / 2;

    // workspace layout (floats)
    float* dis = (float*)d_ws;                 // N      (deg then 1/sqrt(deg))
    float* A   = dis + ((N + 255) & ~255);     // N*HID  (xw1 / xw2)
    float* B   = A + (size_t)N * HID;          // N*HID  (agg1 / h1)
    float* C   = B + (size_t)N * HID;          // N*HID  (agg2 / h2)

    const int nThreads = 256;
    const int gN   = (N + nThreads - 1) / nThreads;
    const int gNH  = (N * HID + nThreads - 1) / nThreads;
    const int gE   = (E + nThreads - 1) / nThreads;
    const int gEH  = (int)(((long long)E * HID + nThreads - 1) / nThreads);
    const int gMLP = (E + 63) / 64;

    // pack split-bf16 weight fragments (device globals)
    k_pack<<<112, nThreads, 0, stream>>>(mW1, mW2);

    // degree + norm (dis buffer)
    k_deg_init<<<gN, nThreads, 0, stream>>>(dis, N);
    k_deg_count<<<gE, nThreads, 0, stream>>>(ei, dis, E);
    k_dis<<<gN, nThreads, 0, stream>>>(dis, N);

    // conv 1
    k_xw1<<<gNH, nThreads, 0, stream>>>(x, W1, A, N);
    hipMemsetAsync(B, 0, (size_t)N * HID * sizeof(float), stream);
    k_scatter<<<gEH, nThreads, 0, stream>>>(A, ei, dis, B, E);
    k_postconv<<<gNH, nThreads, 0, stream>>>(A, B, dis, b1, B, N);  // h1 in B

    // conv 2
    k_xw2<<<gNH, nThreads, 0, stream>>>(B, W2, A, N);
    hipMemsetAsync(C, 0, (size_t)N * HID * sizeof(float), stream);
    k_scatter<<<gEH, nThreads, 0, stream>>>(A, ei, dis, C, E);
    k_postconv<<<gNH, nThreads, 0, stream>>>(A, C, dis, b2, C, N);  // h2 in C

    // edge MLP (MFMA, split-bf16)
    k_edge_mlp<<<gMLP, nThreads, 0, stream>>>(C, ei, ea, mb1, mb2, mW3, mb3, q, E);
}

// Round 5
// 964.672 us; speedup vs baseline: 2.1564x; 1.3888x over previous
//
#include <hip/hip_runtime.h>
#include <hip/hip_bf16.h>

#define HID 64
#define FNODE 16
#define FEDGE 8
#define ZSTR 160  // bf16 elems per LDS row (136 data + pad to 5 ktiles)

typedef __bf16 v8bf __attribute__((ext_vector_type(8)));
typedef unsigned short us8 __attribute__((ext_vector_type(8)));
typedef float v4f __attribute__((ext_vector_type(4)));

// ---------------- packed split-bf16 weight fragments ----------------
// layer1: K padded 136->160 (5 ktiles), N=128 (8 ntiles): frag f=kt*8+nt, elem f*512+lane*8+j
// layer2: K=128 (4 ktiles), N=64 (4 ntiles):              frag f=kt*4+nt
__device__ __bf16 g_w1h[20480];
__device__ __bf16 g_w1l[20480];
__device__ __bf16 g_w2h[8192];
__device__ __bf16 g_w2l[8192];

__global__ void k_pack(const float* __restrict__ mW1, const float* __restrict__ mW2) {
    int gid = blockIdx.x * 256 + threadIdx.x;
    if (gid < 20480) {
        int j = gid & 7, lane = (gid >> 3) & 63, f = gid >> 9;
        int kt = f >> 3, nt = f & 7;
        int k = kt * 32 + (lane >> 4) * 8 + j;
        int col = nt * 16 + (lane & 15);
        float x = (k < 136) ? mW1[k * 128 + col] : 0.f;
        __bf16 hi = (__bf16)x;
        g_w1h[gid] = hi;
        g_w1l[gid] = (__bf16)(x - (float)hi);
    } else if (gid < 28672) {
        int t = gid - 20480;
        int j = t & 7, lane = (t >> 3) & 63, f = t >> 9;
        int kt = f >> 2, nt = f & 3;
        int k = kt * 32 + (lane >> 4) * 8 + j;
        int col = nt * 16 + (lane & 15);
        float x = mW2[k * 64 + col];
        __bf16 hi = (__bf16)x;
        g_w2h[t] = hi;
        g_w2l[t] = (__bf16)(x - (float)hi);
    }
}

// ---------------- CSR build ----------------
__global__ void k_count(const int* __restrict__ ei, int* __restrict__ cnt, int E) {
    int e = blockIdx.x * 256 + threadIdx.x;
    if (e < E) atomicAdd(&cnt[ei[E + e]], 1);
}

__global__ void k_disn(const int* __restrict__ cnt, float* __restrict__ dis, int N) {
    int n = blockIdx.x * 256 + threadIdx.x;
    if (n < N) dis[n] = rsqrtf((float)(cnt[n] + 1));  // +1 self-loop
}

__device__ __forceinline__ int block_scan_excl(int v, int* wsum) {
    int lane = threadIdx.x & 63, wv = threadIdx.x >> 6;
    int inc = v;
#pragma unroll
    for (int d = 1; d < 64; d <<= 1) {
        int t = __shfl_up(inc, d, 64);
        if (lane >= d) inc += t;
    }
    if (lane == 63) wsum[wv] = inc;
    __syncthreads();
    int off = 0;
    for (int w = 0; w < wv; ++w) off += wsum[w];
    return off + inc - v;  // exclusive
}

__global__ void k_scan1(const int* __restrict__ cnt, int* __restrict__ rp,
                        int* __restrict__ bsum, int N) {
    __shared__ int ws[4];
    int i = blockIdx.x * 256 + threadIdx.x;
    int v = (i < N) ? cnt[i] : 0;
    int excl = block_scan_excl(v, ws);
    if (i < N) rp[i] = excl;
    if (threadIdx.x == 255) bsum[blockIdx.x] = excl + v;
}

__global__ void k_scan2(int* __restrict__ bsum, int nb) {
    __shared__ int ws[4];
    int i = threadIdx.x;
    int v = (i < nb) ? bsum[i] : 0;
    int excl = block_scan_excl(v, ws);
    if (i < nb) bsum[i] = excl;
}

__global__ void k_scan3(int* __restrict__ rp, int* __restrict__ cur,
                        const int* __restrict__ bsum, int N, int E) {
    int i = blockIdx.x * 256 + threadIdx.x;
    if (i < N) {
        int r = rp[i] + bsum[i >> 8];
        rp[i] = r;
        cur[i] = r;
        if (i == N - 1) rp[N] = E;
    }
}

__global__ void k_fill(const int* __restrict__ ei, int* __restrict__ cur,
                       int* __restrict__ col, int E) {
    int e = blockIdx.x * 256 + threadIdx.x;
    if (e < E) {
        int d = ei[E + e];
        int pos = atomicAdd(&cur[d], 1);
        col[pos] = ei[e];  // src
    }
}

// ---------------- y = (x @ W) * dis[n]  ----------------
__global__ __launch_bounds__(256) void k_xw1y(const float* __restrict__ x,
                                              const float* __restrict__ W,
                                              const float* __restrict__ dis,
                                              float* __restrict__ y, int N) {
    int t = blockIdx.x * 256 + threadIdx.x;
    int n = t >> 6, h = t & 63;
    if (n >= N) return;
    float acc = 0.f;
#pragma unroll
    for (int k = 0; k < FNODE; ++k) acc += x[n * FNODE + k] * W[k * HID + h];
    y[t] = acc * dis[n];
}

__global__ __launch_bounds__(256) void k_xw2y(const float* __restrict__ h,
                                              const float* __restrict__ W,
                                              const float* __restrict__ dis,
                                              float* __restrict__ y, int N) {
    int t = blockIdx.x * 256 + threadIdx.x;
    int n = t >> 6, hh = t & 63;
    if (n >= N) return;
    float acc = 0.f;
#pragma unroll
    for (int k = 0; k < HID; ++k) acc += h[n * HID + k] * W[k * HID + hh];
    y[t] = acc * dis[n];
}

// ---------------- pull aggregation: out = relu(dis[n]*(sum y[col] + y[n]) + b)
__global__ __launch_bounds__(256) void k_pull1(const float* __restrict__ y,
                                               const int* __restrict__ rp,
                                               const int* __restrict__ col,
                                               const float* __restrict__ dis,
                                               const float* __restrict__ b,
                                               float* __restrict__ out, int N) {
    int wave = threadIdx.x >> 6, lane = threadIdx.x & 63;
    int n = blockIdx.x * 4 + wave;
    if (n >= N) return;
    int beg = rp[n], end = rp[n + 1];
    float acc = y[(size_t)n * HID + lane];  // self term
    for (int j = beg; j < end; ++j) {
        int s = col[j];
        acc += y[(size_t)s * HID + lane];
    }
    out[(size_t)n * HID + lane] = fmaxf(dis[n] * acc + b[lane], 0.f);
}

// pull2: same, but emit hi/lo bf16 planes packed per node: hp[n][0..63]=hi, [64..127]=lo
__global__ __launch_bounds__(256) void k_pull2(const float* __restrict__ y,
                                               const int* __restrict__ rp,
                                               const int* __restrict__ col,
                                               const float* __restrict__ dis,
                                               const float* __restrict__ b,
                                               __bf16* __restrict__ hp, int N) {
    int wave = threadIdx.x >> 6, lane = threadIdx.x & 63;
    int n = blockIdx.x * 4 + wave;
    if (n >= N) return;
    int beg = rp[n], end = rp[n + 1];
    float acc = y[(size_t)n * HID + lane];
    for (int j = beg; j < end; ++j) {
        int s = col[j];
        acc += y[(size_t)s * HID + lane];
    }
    float v = fmaxf(dis[n] * acc + b[lane], 0.f);
    __bf16 hi = (__bf16)v;
    __bf16* p = hp + (size_t)n * 128;
    p[lane] = hi;
    p[64 + lane] = (__bf16)(v - (float)hi);
}

// ---------------- edge MLP via split-bf16 MFMA ----------------
// block = 256 threads (4 waves) = 64 edges. LDS exactly 40KB -> 4 blocks/CU.
__global__ __launch_bounds__(256) void k_edge_mlp(
    const __bf16* __restrict__ hp, const int* __restrict__ ei,
    const float* __restrict__ ea,
    const float* __restrict__ mb1, const float* __restrict__ mb2,
    const float* __restrict__ mW3, const float* __restrict__ mb3,
    float* __restrict__ q, int E) {
    __shared__ __align__(16) __bf16 zh[64][ZSTR];
    __shared__ __align__(16) __bf16 zl[64][ZSTR];

    const int tid = threadIdx.x;
    const int lane = tid & 63;
    const int wave = tid >> 6;
    const int g = lane >> 4;   // 16-lane group
    const int cb = lane & 15;  // row/col base within 16
    const int m0 = blockIdx.x * 64;

    // ---- stage: pure 16B copies from packed hi/lo planes (no conversion).
    // Node plane = 128 bf16 = 16 us8 chunks: chunks 0-7 = hi(64), 8-15 = lo(64).
    // 4 threads/edge, each moves 4 chunks of src + 4 chunks of dst.
    {
        const int m = tid >> 2, qt = tid & 3;
        const int e = m0 + m;
        const bool valid = e < E;
        const int s = valid ? ei[e] : 0;
        const int d = valid ? ei[E + e] : 0;
        const us8* S = (const us8*)(hp + (size_t)s * 128);
        const us8* D = (const us8*)(hp + (size_t)d * 128);
#pragma unroll
        for (int cc = 0; cc < 4; ++cc) {
            int c = qt * 4 + cc;  // 0..15
            us8 vs = S[c];
            us8 vd = D[c];
            __bf16* dst = (c < 8) ? &zh[m][0] : &zl[m][0];
            int base = (c & 7) * 8;  // element offset within plane
            *(us8*)&dst[base] = vs;         // src -> cols [0,64)
            *(us8*)&dst[64 + base] = vd;    // dst -> cols [64,128)
        }
        if (qt < 2) {
            float buf[8];
#pragma unroll
            for (int i = 0; i < 8; ++i) buf[i] = valid ? ea[(size_t)e * FEDGE + i] : 0.f;
            __bf16* dst = qt ? &zl[m][0] : &zh[m][0];
            if (qt == 0) {
#pragma unroll
                for (int i = 0; i < 8; ++i) dst[128 + i] = (__bf16)buf[i];
            } else {
#pragma unroll
                for (int i = 0; i < 8; ++i) {
                    __bf16 h = (__bf16)buf[i];
                    dst[128 + i] = (__bf16)(buf[i] - (float)h);
                }
            }
            us8 zz = {};
#pragma unroll
            for (int c = 136; c < 160; c += 8) *(us8*)&dst[c] = zz;
        }
    }
    __syncthreads();

    // ---- layer 1: wave owns col-tiles nt0, nt0+1 (32 of 128 cols), all 64 edges
    const int nt0 = wave * 2;
    v4f acc[2][4];
    {
        float b0 = mb1[nt0 * 16 + cb];
        float b1 = mb1[nt0 * 16 + 16 + cb];
#pragma unroll
        for (int mt = 0; mt < 4; ++mt) {
            acc[0][mt] = (v4f){b0, b0, b0, b0};
            acc[1][mt] = (v4f){b1, b1, b1, b1};
        }
    }
    const v8bf* w1h = (const v8bf*)g_w1h;
    const v8bf* w1l = (const v8bf*)g_w1l;
#pragma unroll
    for (int kt = 0; kt < 5; ++kt) {
        v8bf bh0 = w1h[(kt * 8 + nt0) * 64 + lane];
        v8bf bl0 = w1l[(kt * 8 + nt0) * 64 + lane];
        v8bf bh1 = w1h[(kt * 8 + nt0 + 1) * 64 + lane];
        v8bf bl1 = w1l[(kt * 8 + nt0 + 1) * 64 + lane];
#pragma unroll
        for (int mt = 0; mt < 4; ++mt) {
            v8bf ah = *(const v8bf*)&zh[mt * 16 + cb][kt * 32 + g * 8];
            v8bf al = *(const v8bf*)&zl[mt * 16 + cb][kt * 32 + g * 8];
            acc[0][mt] = __builtin_amdgcn_mfma_f32_16x16x32_bf16(ah, bh0, acc[0][mt], 0, 0, 0);
            acc[0][mt] = __builtin_amdgcn_mfma_f32_16x16x32_bf16(ah, bl0, acc[0][mt], 0, 0, 0);
            acc[0][mt] = __builtin_amdgcn_mfma_f32_16x16x32_bf16(al, bh0, acc[0][mt], 0, 0, 0);
            acc[1][mt] = __builtin_amdgcn_mfma_f32_16x16x32_bf16(ah, bh1, acc[1][mt], 0, 0, 0);
            acc[1][mt] = __builtin_amdgcn_mfma_f32_16x16x32_bf16(ah, bl1, acc[1][mt], 0, 0, 0);
            acc[1][mt] = __builtin_amdgcn_mfma_f32_16x16x32_bf16(al, bh1, acc[1][mt], 0, 0, 0);
        }
    }
    __syncthreads();  // everyone done reading z before overwriting with z1

    // ---- write z1 = relu(acc) split into cols [nt0*16, nt0*16+32)
    // D layout (m89-verified): col = lane&15, row = (lane>>4)*4 + reg
#pragma unroll
    for (int c = 0; c < 2; ++c)
#pragma unroll
        for (int mt = 0; mt < 4; ++mt)
#pragma unroll
            for (int r = 0; r < 4; ++r) {
                float vv = fmaxf(acc[c][mt][r], 0.f);
                __bf16 hi = (__bf16)vv;
                int row = mt * 16 + g * 4 + r;
                int colx = (nt0 + c) * 16 + cb;
                zh[row][colx] = hi;
                zl[row][colx] = (__bf16)(vv - (float)hi);
            }
    __syncthreads();

    // ---- layer 2: wave owns col-tile nt=wave (16 of 64 cols), all 64 edges
    v4f acc2[4];
    {
        float b = mb2[wave * 16 + cb];
#pragma unroll
        for (int mt = 0; mt < 4; ++mt) acc2[mt] = (v4f){b, b, b, b};
    }
    const v8bf* w2h = (const v8bf*)g_w2h;
    const v8bf* w2l = (const v8bf*)g_w2l;
#pragma unroll
    for (int kt = 0; kt < 4; ++kt) {
        v8bf bh = w2h[(kt * 4 + wave) * 64 + lane];
        v8bf bl = w2l[(kt * 4 + wave) * 64 + lane];
#pragma unroll
        for (int mt = 0; mt < 4; ++mt) {
            v8bf ah = *(const v8bf*)&zh[mt * 16 + cb][kt * 32 + g * 8];
            v8bf al = *(const v8bf*)&zl[mt * 16 + cb][kt * 32 + g * 8];
            acc2[mt] = __builtin_amdgcn_mfma_f32_16x16x32_bf16(ah, bh, acc2[mt], 0, 0, 0);
            acc2[mt] = __builtin_amdgcn_mfma_f32_16x16x32_bf16(ah, bl, acc2[mt], 0, 0, 0);
            acc2[mt] = __builtin_amdgcn_mfma_f32_16x16x32_bf16(al, bh, acc2[mt], 0, 0, 0);
        }
    }
    __syncthreads();  // all z reads done -> safe to overlay qpart on zh

    // ---- layer 3: q = relu(z2) @ mW3 + mb3; shfl-reduce 16 cols, cross-wave via LDS
    float* qp = (float*)&zh[0][0];  // [4][64] overlay
    const float w3 = mW3[wave * 16 + cb];
#pragma unroll
    for (int mt = 0; mt < 4; ++mt) {
#pragma unroll
        for (int r = 0; r < 4; ++r) {
            float pr = fmaxf(acc2[mt][r], 0.f) * w3;
            pr += __shfl_xor(pr, 1, 16);
            pr += __shfl_xor(pr, 2, 16);
            pr += __shfl_xor(pr, 4, 16);
            pr += __shfl_xor(pr, 8, 16);
            if (cb == 0) qp[wave * 64 + mt * 16 + g * 4 + r] = pr;
        }
    }
    __syncthreads();
    if (tid < 64) {
        int e = m0 + tid;
        if (e < E)
            q[e] = qp[tid] + qp[64 + tid] + qp[128 + tid] + qp[192 + tid] + mb3[0];
    }
}

extern "C" void kernel_launch(void* const* d_in, const int* in_sizes, int n_in,
                              void* d_out, int out_size, void* d_ws, size_t ws_size,
                              hipStream_t stream) {
    const float* x   = (const float*)d_in[0];
    const int*   ei  = (const int*)d_in[1];
    const float* ea  = (const float*)d_in[2];
    const float* W1  = (const float*)d_in[3];
    const float* b1  = (const float*)d_in[4];
    const float* W2  = (const float*)d_in[5];
    const float* b2  = (const float*)d_in[6];
    const float* mW1 = (const float*)d_in[7];
    const float* mb1 = (const float*)d_in[8];
    const float* mW2 = (const float*)d_in[9];
    const float* mb2 = (const float*)d_in[10];
    const float* mW3 = (const float*)d_in[11];
    const float* mb3 = (const float*)d_in[12];
    float* q = (float*)d_out;

    const int N = in_sizes[0] / FNODE;
    const int E = in_sizes[1] / 2;

    // workspace layout (float units)
    float* dis = (float*)d_ws;                      // N (padded)
    float* A = dis + ((N + 255) & ~255);            // N*HID  (y1 / y2)
    float* B = A + (size_t)N * HID;                 // N*HID  (h1 fp32, then hi/lo planes)
    float* Cf = B + (size_t)N * HID;                // CSR ints region
    int* rp   = (int*)Cf;                           // N+1
    int* cur  = rp + ((N + 1 + 255) & ~255);        // N
    int* col  = cur + ((N + 255) & ~255);           // E
    int* bsum = col + E;                            // 256

    const int nT = 256;
    const int gN   = (N + nT - 1) / nT;             // 196
    const int gE   = (E + nT - 1) / nT;             // 6250
    const int gNH  = (N * HID + nT - 1) / nT;       // 12500
    const int gPull = (N + 3) / 4;                  // 12500
    const int gMLP = (E + 63) / 64;                 // 25000

    // pack split-bf16 weight fragments
    k_pack<<<112, nT, 0, stream>>>(mW1, mW2);

    // CSR build (by dst) + dis
    hipMemsetAsync(cur, 0, (size_t)N * sizeof(int), stream);
    k_count<<<gE, nT, 0, stream>>>(ei, cur, E);
    k_disn<<<gN, nT, 0, stream>>>(cur, dis, N);
    k_scan1<<<gN, nT, 0, stream>>>(cur, rp, bsum, N);
    k_scan2<<<1, nT, 0, stream>>>(bsum, gN);
    k_scan3<<<gN, nT, 0, stream>>>(rp, cur, bsum, N, E);
    k_fill<<<gE, nT, 0, stream>>>(ei, cur, col, E);

    // conv 1: y1 = (x@W1)*dis  ->  h1 = relu(dis*(sum+self)+b1) in B (fp32)
    k_xw1y<<<gNH, nT, 0, stream>>>(x, W1, dis, A, N);
    k_pull1<<<gPull, nT, 0, stream>>>(A, rp, col, dis, b1, B, N);

    // conv 2: y2 = (h1@W2)*dis ->  h2 as hi/lo bf16 planes in B
    k_xw2y<<<gNH, nT, 0, stream>>>(B, W2, dis, A, N);
    k_pull2<<<gPull, nT, 0, stream>>>(A, rp, col, dis, b2, (__bf16*)B, N);

    // edge MLP (MFMA, split-bf16, staged from packed planes)
    k_edge_mlp<<<gMLP, nT, 0, stream>>>((const __bf16*)B, ei, ea, mb1, mb2, mW3,
                                        mb3, q, E);
}

// Round 6
// 757.252 us; speedup vs baseline: 2.7471x; 1.2739x over previous
//
#include <hip/hip_runtime.h>
#include <hip/hip_bf16.h>

#define HID 64
#define FNODE 16
#define FEDGE 8
#define ZSTR 160  // bf16 elems per LDS row (136 data + pad to 5 ktiles)

typedef __bf16 v8bf __attribute__((ext_vector_type(8)));
typedef unsigned short us8 __attribute__((ext_vector_type(8)));
typedef float v4f __attribute__((ext_vector_type(4)));

// ---------------- packed split-bf16 weight fragments ----------------
// layer1: K padded 136->160 (5 ktiles), N=128 (8 ntiles): frag f=kt*8+nt, elem f*512+lane*8+j
// layer2: K=128 (4 ktiles), N=64 (4 ntiles):              frag f=kt*4+nt
__device__ __bf16 g_w1h[20480];
__device__ __bf16 g_w1l[20480];
__device__ __bf16 g_w2h[8192];
__device__ __bf16 g_w2l[8192];

__global__ void k_pack(const float* __restrict__ mW1, const float* __restrict__ mW2) {
    int gid = blockIdx.x * 256 + threadIdx.x;
    if (gid < 20480) {
        int j = gid & 7, lane = (gid >> 3) & 63, f = gid >> 9;
        int kt = f >> 3, nt = f & 7;
        int k = kt * 32 + (lane >> 4) * 8 + j;
        int col = nt * 16 + (lane & 15);
        float x = (k < 136) ? mW1[k * 128 + col] : 0.f;
        __bf16 hi = (__bf16)x;
        g_w1h[gid] = hi;
        g_w1l[gid] = (__bf16)(x - (float)hi);
    } else if (gid < 28672) {
        int t = gid - 20480;
        int j = t & 7, lane = (t >> 3) & 63, f = t >> 9;
        int kt = f >> 2, nt = f & 3;
        int k = kt * 32 + (lane >> 4) * 8 + j;
        int col = nt * 16 + (lane & 15);
        float x = mW2[k * 64 + col];
        __bf16 hi = (__bf16)x;
        g_w2h[t] = hi;
        g_w2l[t] = (__bf16)(x - (float)hi);
    }
}

// ---------------- CSR build (rp doubles as count, then starts, then cursor) ----
__global__ void k_count(const int* __restrict__ ei, int* __restrict__ rp, int E) {
    int e = blockIdx.x * 256 + threadIdx.x;
    if (e < E) atomicAdd(&rp[ei[E + e]], 1);
}

__global__ void k_disn(const int* __restrict__ rp, float* __restrict__ dis, int N) {
    int n = blockIdx.x * 256 + threadIdx.x;
    if (n < N) dis[n] = rsqrtf((float)(rp[n] + 1));  // +1 self-loop
}

__device__ __forceinline__ int block_scan_excl(int v, int* wsum) {
    int lane = threadIdx.x & 63, wv = threadIdx.x >> 6;
    int inc = v;
#pragma unroll
    for (int d = 1; d < 64; d <<= 1) {
        int t = __shfl_up(inc, d, 64);
        if (lane >= d) inc += t;
    }
    if (lane == 63) wsum[wv] = inc;
    __syncthreads();
    int off = 0;
    for (int w = 0; w < wv; ++w) off += wsum[w];
    return off + inc - v;  // exclusive
}

__global__ void k_scan1(int* __restrict__ rp, int* __restrict__ bsum, int N) {
    __shared__ int ws[4];
    int i = blockIdx.x * 256 + threadIdx.x;
    int v = (i < N) ? rp[i] : 0;
    int excl = block_scan_excl(v, ws);
    if (i < N) rp[i] = excl;
    if (threadIdx.x == 255) bsum[blockIdx.x] = excl + v;
}

__global__ void k_scan2(int* __restrict__ bsum, int nb) {
    __shared__ int ws[4];
    int i = threadIdx.x;
    int v = (i < nb) ? bsum[i] : 0;
    int excl = block_scan_excl(v, ws);
    if (i < nb) bsum[i] = excl;
}

__global__ void k_scan3(int* __restrict__ rp, const int* __restrict__ bsum, int N) {
    int i = blockIdx.x * 256 + threadIdx.x;
    if (i < N) rp[i] += bsum[i >> 8];
}

// fill: rp[d] is the cursor; post-fill rp[d] == start(d+1), so
// row d = [ (d? rp[d-1] : 0), rp[d] ).
__global__ void k_fill(const int* __restrict__ ei, int* __restrict__ rp,
                       int* __restrict__ ce, int* __restrict__ eid, int E) {
    int e = blockIdx.x * 256 + threadIdx.x;
    if (e < E) {
        int s = ei[e], d = ei[E + e];
        int pos = atomicAdd(&rp[d], 1);
        ce[pos] = s | (d << 16);
        eid[pos] = e;
    }
}

// ---------------- conv1 in x-space: dx = dis*x (rows 64 B) ----------------
__global__ void k_dx(const float* __restrict__ x, const float* __restrict__ dis,
                     float* __restrict__ dx, int NF) {
    int t = blockIdx.x * 256 + threadIdx.x;
    if (t < NF) dx[t] = x[t] * dis[t >> 4];
}

// u[n] = dis[n]*(sum_{s in in(n)} dx[s] + dx[n])   (16-dim gather, 64 B rows)
__global__ __launch_bounds__(256) void k_pull1x(const float* __restrict__ dx,
                                                const int* __restrict__ rp,
                                                const int* __restrict__ ce,
                                                const float* __restrict__ dis,
                                                float* __restrict__ u, int N) {
    int grp = threadIdx.x >> 4, dim = threadIdx.x & 15;
    int n = blockIdx.x * 16 + grp;
    if (n >= N) return;
    int beg = n ? rp[n - 1] : 0;
    int end = rp[n];
    float a0 = dx[(size_t)n * 16 + dim];  // self
    float a1 = 0.f, a2 = 0.f, a3 = 0.f;
    int j = beg;
    for (; j + 3 < end; j += 4) {
        int s0 = ce[j] & 0xffff, s1 = ce[j + 1] & 0xffff;
        int s2 = ce[j + 2] & 0xffff, s3 = ce[j + 3] & 0xffff;
        a0 += dx[(size_t)s0 * 16 + dim];
        a1 += dx[(size_t)s1 * 16 + dim];
        a2 += dx[(size_t)s2 * 16 + dim];
        a3 += dx[(size_t)s3 * 16 + dim];
    }
    for (; j < end; ++j) a0 += dx[(size_t)(ce[j] & 0xffff) * 16 + dim];
    u[(size_t)n * 16 + dim] = dis[n] * ((a0 + a1) + (a2 + a3));
}

// h1 = relu(u@W1+b1) (per-node, in-wave), then y2 = dis*(h1@W2) -- fused
__global__ __launch_bounds__(256) void k_h1y2(const float* __restrict__ u,
                                              const float* __restrict__ W1,
                                              const float* __restrict__ b1,
                                              const float* __restrict__ W2,
                                              const float* __restrict__ dis,
                                              float* __restrict__ y2, int N) {
    __shared__ float sh[4][64];
    int wave = threadIdx.x >> 6, lane = threadIdx.x & 63;
    int n = blockIdx.x * 4 + wave;
    if (n >= N) return;
    float myu = u[(size_t)n * 16 + (lane & 15)];  // lane k<16 holds u[k]
    float h = b1[lane];
#pragma unroll
    for (int k = 0; k < 16; ++k)
        h = fmaf(__shfl(myu, k, 64), W1[k * HID + lane], h);
    h = fmaxf(h, 0.f);
    sh[wave][lane] = h;  // wave-synchronous LDS: no barrier needed
    float acc = 0.f;
#pragma unroll 8
    for (int k = 0; k < HID; ++k)
        acc = fmaf(sh[wave][k], W2[k * HID + lane], acc);
    y2[(size_t)n * HID + lane] = dis[n] * acc;
}

// h2 = relu(dis[n]*(sum y2[s] + y2[n]) + b2) -> hi/lo bf16 planes hp[n][0..127]
__global__ __launch_bounds__(256) void k_pull2(const float* __restrict__ y,
                                               const int* __restrict__ rp,
                                               const int* __restrict__ ce,
                                               const float* __restrict__ dis,
                                               const float* __restrict__ b,
                                               __bf16* __restrict__ hp, int N) {
    int wave = threadIdx.x >> 6, lane = threadIdx.x & 63;
    int n = blockIdx.x * 4 + wave;
    if (n >= N) return;
    int beg = n ? rp[n - 1] : 0;
    int end = rp[n];
    float a0 = y[(size_t)n * HID + lane];  // self
    float a1 = 0.f, a2 = 0.f, a3 = 0.f;
    int j = beg;
    for (; j + 3 < end; j += 4) {
        int s0 = ce[j] & 0xffff, s1 = ce[j + 1] & 0xffff;
        int s2 = ce[j + 2] & 0xffff, s3 = ce[j + 3] & 0xffff;
        a0 += y[(size_t)s0 * HID + lane];
        a1 += y[(size_t)s1 * HID + lane];
        a2 += y[(size_t)s2 * HID + lane];
        a3 += y[(size_t)s3 * HID + lane];
    }
    for (; j < end; ++j) a0 += y[(size_t)(ce[j] & 0xffff) * HID + lane];
    float v = fmaxf(dis[n] * ((a0 + a1) + (a2 + a3)) + b[lane], 0.f);
    __bf16 hi = (__bf16)v;
    __bf16* p = hp + (size_t)n * 128;
    p[lane] = hi;
    p[64 + lane] = (__bf16)(v - (float)hi);
}

// ---------------- edge MLP via split-bf16 MFMA, CSR (dst-grouped) order -----
// block = 256 threads (4 waves) = 64 CSR positions. dst rows repeat within a
// block -> L1 hits; src random; ea/q scattered via eid. LDS 40KB -> 4 blk/CU.
__global__ __launch_bounds__(256) void k_edge_mlp(
    const __bf16* __restrict__ hp, const int* __restrict__ ce,
    const int* __restrict__ eid, const float* __restrict__ ea,
    const float* __restrict__ mb1, const float* __restrict__ mb2,
    const float* __restrict__ mW3, const float* __restrict__ mb3,
    float* __restrict__ q, int E) {
    __shared__ __align__(16) __bf16 zh[64][ZSTR];
    __shared__ __align__(16) __bf16 zl[64][ZSTR];

    const int tid = threadIdx.x;
    const int lane = tid & 63;
    const int wave = tid >> 6;
    const int g = lane >> 4;   // 16-lane group
    const int cb = lane & 15;  // row/col base within 16
    const int m0 = blockIdx.x * 64;

    // ---- stage: 16B copies from packed hi/lo planes.
    // Node plane = 128 bf16 = 16 us8 chunks: 0-7 = hi, 8-15 = lo.
    {
        const int m = tid >> 2, qt = tid & 3;
        const int p = m0 + m;
        const bool valid = p < E;
        const int cep = valid ? ce[p] : 0;
        const int e = valid ? eid[p] : 0;
        const int s = cep & 0xffff;
        const int d = ((unsigned)cep) >> 16;
        const us8* S = (const us8*)(hp + (size_t)s * 128);
        const us8* D = (const us8*)(hp + (size_t)d * 128);
#pragma unroll
        for (int cc = 0; cc < 4; ++cc) {
            int c = qt * 4 + cc;  // 0..15
            us8 vs = S[c];
            us8 vd = D[c];
            __bf16* dst = (c < 8) ? &zh[m][0] : &zl[m][0];
            int base = (c & 7) * 8;
            *(us8*)&dst[base] = vs;       // src -> cols [0,64)
            *(us8*)&dst[64 + base] = vd;  // dst -> cols [64,128)
        }
        if (qt < 2) {
            float buf[8];
#pragma unroll
            for (int i = 0; i < 8; ++i) buf[i] = valid ? ea[(size_t)e * FEDGE + i] : 0.f;
            __bf16* dst = qt ? &zl[m][0] : &zh[m][0];
            if (qt == 0) {
#pragma unroll
                for (int i = 0; i < 8; ++i) dst[128 + i] = (__bf16)buf[i];
            } else {
#pragma unroll
                for (int i = 0; i < 8; ++i) {
                    __bf16 h = (__bf16)buf[i];
                    dst[128 + i] = (__bf16)(buf[i] - (float)h);
                }
            }
            us8 zz = {};
#pragma unroll
            for (int c = 136; c < 160; c += 8) *(us8*)&dst[c] = zz;
        }
    }
    __syncthreads();

    // ---- layer 1: wave owns col-tiles nt0, nt0+1 (32 of 128 cols)
    const int nt0 = wave * 2;
    v4f acc[2][4];
    {
        float b0 = mb1[nt0 * 16 + cb];
        float b1v = mb1[nt0 * 16 + 16 + cb];
#pragma unroll
        for (int mt = 0; mt < 4; ++mt) {
            acc[0][mt] = (v4f){b0, b0, b0, b0};
            acc[1][mt] = (v4f){b1v, b1v, b1v, b1v};
        }
    }
    const v8bf* w1h = (const v8bf*)g_w1h;
    const v8bf* w1l = (const v8bf*)g_w1l;
#pragma unroll
    for (int kt = 0; kt < 5; ++kt) {
        v8bf bh0 = w1h[(kt * 8 + nt0) * 64 + lane];
        v8bf bl0 = w1l[(kt * 8 + nt0) * 64 + lane];
        v8bf bh1 = w1h[(kt * 8 + nt0 + 1) * 64 + lane];
        v8bf bl1 = w1l[(kt * 8 + nt0 + 1) * 64 + lane];
#pragma unroll
        for (int mt = 0; mt < 4; ++mt) {
            v8bf ah = *(const v8bf*)&zh[mt * 16 + cb][kt * 32 + g * 8];
            v8bf al = *(const v8bf*)&zl[mt * 16 + cb][kt * 32 + g * 8];
            acc[0][mt] = __builtin_amdgcn_mfma_f32_16x16x32_bf16(ah, bh0, acc[0][mt], 0, 0, 0);
            acc[0][mt] = __builtin_amdgcn_mfma_f32_16x16x32_bf16(ah, bl0, acc[0][mt], 0, 0, 0);
            acc[0][mt] = __builtin_amdgcn_mfma_f32_16x16x32_bf16(al, bh0, acc[0][mt], 0, 0, 0);
            acc[1][mt] = __builtin_amdgcn_mfma_f32_16x16x32_bf16(ah, bh1, acc[1][mt], 0, 0, 0);
            acc[1][mt] = __builtin_amdgcn_mfma_f32_16x16x32_bf16(ah, bl1, acc[1][mt], 0, 0, 0);
            acc[1][mt] = __builtin_amdgcn_mfma_f32_16x16x32_bf16(al, bh1, acc[1][mt], 0, 0, 0);
        }
    }
    __syncthreads();  // everyone done reading z before overwriting with z1

    // ---- write z1 = relu(acc) split into cols [nt0*16, nt0*16+32)
    // D layout (m89-verified): col = lane&15, row = (lane>>4)*4 + reg
#pragma unroll
    for (int c = 0; c < 2; ++c)
#pragma unroll
        for (int mt = 0; mt < 4; ++mt)
#pragma unroll
            for (int r = 0; r < 4; ++r) {
                float vv = fmaxf(acc[c][mt][r], 0.f);
                __bf16 hi = (__bf16)vv;
                int row = mt * 16 + g * 4 + r;
                int colx = (nt0 + c) * 16 + cb;
                zh[row][colx] = hi;
                zl[row][colx] = (__bf16)(vv - (float)hi);
            }
    __syncthreads();

    // ---- layer 2: wave owns col-tile nt=wave (16 of 64 cols)
    v4f acc2[4];
    {
        float b = mb2[wave * 16 + cb];
#pragma unroll
        for (int mt = 0; mt < 4; ++mt) acc2[mt] = (v4f){b, b, b, b};
    }
    const v8bf* w2h = (const v8bf*)g_w2h;
    const v8bf* w2l = (const v8bf*)g_w2l;
#pragma unroll
    for (int kt = 0; kt < 4; ++kt) {
        v8bf bh = w2h[(kt * 4 + wave) * 64 + lane];
        v8bf bl = w2l[(kt * 4 + wave) * 64 + lane];
#pragma unroll
        for (int mt = 0; mt < 4; ++mt) {
            v8bf ah = *(const v8bf*)&zh[mt * 16 + cb][kt * 32 + g * 8];
            v8bf al = *(const v8bf*)&zl[mt * 16 + cb][kt * 32 + g * 8];
            acc2[mt] = __builtin_amdgcn_mfma_f32_16x16x32_bf16(ah, bh, acc2[mt], 0, 0, 0);
            acc2[mt] = __builtin_amdgcn_mfma_f32_16x16x32_bf16(ah, bl, acc2[mt], 0, 0, 0);
            acc2[mt] = __builtin_amdgcn_mfma_f32_16x16x32_bf16(al, bh, acc2[mt], 0, 0, 0);
        }
    }
    __syncthreads();  // all z reads done -> overlay qpart on zh

    // ---- layer 3: shfl-reduce 16 cols per wave, cross-wave via LDS
    float* qp = (float*)&zh[0][0];  // [4][64] overlay
    const float w3 = mW3[wave * 16 + cb];
#pragma unroll
    for (int mt = 0; mt < 4; ++mt) {
#pragma unroll
        for (int r = 0; r < 4; ++r) {
            float pr = fmaxf(acc2[mt][r], 0.f) * w3;
            pr += __shfl_xor(pr, 1, 16);
            pr += __shfl_xor(pr, 2, 16);
            pr += __shfl_xor(pr, 4, 16);
            pr += __shfl_xor(pr, 8, 16);
            if (cb == 0) qp[wave * 64 + mt * 16 + g * 4 + r] = pr;
        }
    }
    __syncthreads();
    if (tid < 64) {
        int p = m0 + tid;
        if (p < E)
            q[eid[p]] = qp[tid] + qp[64 + tid] + qp[128 + tid] + qp[192 + tid] +
                        mb3[0];
    }
}

extern "C" void kernel_launch(void* const* d_in, const int* in_sizes, int n_in,
                              void* d_out, int out_size, void* d_ws, size_t ws_size,
                              hipStream_t stream) {
    const float* x   = (const float*)d_in[0];
    const int*   ei  = (const int*)d_in[1];
    const float* ea  = (const float*)d_in[2];
    const float* W1  = (const float*)d_in[3];
    const float* b1  = (const float*)d_in[4];
    const float* W2  = (const float*)d_in[5];
    const float* b2  = (const float*)d_in[6];
    const float* mW1 = (const float*)d_in[7];
    const float* mb1 = (const float*)d_in[8];
    const float* mW2 = (const float*)d_in[9];
    const float* mb2 = (const float*)d_in[10];
    const float* mW3 = (const float*)d_in[11];
    const float* mb3 = (const float*)d_in[12];
    float* q = (float*)d_out;

    const int N = in_sizes[0] / FNODE;
    const int E = in_sizes[1] / 2;

    // workspace layout (float units)
    float* dis = (float*)d_ws;                        // N (padded, +bsum tail)
    int* bsum  = (int*)(dis + 50000);                 // 256 (in dis pad)
    float* y2  = dis + ((N + 511) & ~255);            // N*HID
    float* hpf = y2 + (size_t)N * HID;                // N*128 bf16 == N*64 floats
    float* dx  = hpf;                                 // N*16 (overlay, dead pre-pull2)
    float* u   = hpf + (size_t)N * 16;                // N*16 (overlay, dead pre-pull2)
    int* rp    = (int*)(hpf + (size_t)N * HID);       // N
    int* ce    = rp + ((N + 255) & ~255);             // E
    int* eid   = ce + E;                              // E

    const int nT = 256;
    const int gN    = (N + nT - 1) / nT;              // 196
    const int gE    = (E + nT - 1) / nT;              // 6250
    const int gNF   = (N * FNODE + nT - 1) / nT;      // 3125
    const int g16   = (N + 15) / 16;                  // 3125
    const int gNode = (N + 3) / 4;                    // 12500
    const int gMLP  = (E + 63) / 64;                  // 25000

    // pack split-bf16 weight fragments
    k_pack<<<112, nT, 0, stream>>>(mW1, mW2);

    // CSR build (by dst) + dis;  rp: counts -> starts -> fill-cursor
    hipMemsetAsync(rp, 0, (size_t)N * sizeof(int), stream);
    k_count<<<gE, nT, 0, stream>>>(ei, rp, E);
    k_disn<<<gN, nT, 0, stream>>>(rp, dis, N);
    k_scan1<<<gN, nT, 0, stream>>>(rp, bsum, N);
    k_scan2<<<1, nT, 0, stream>>>(bsum, gN);
    k_scan3<<<gN, nT, 0, stream>>>(rp, bsum, N);
    k_fill<<<gE, nT, 0, stream>>>(ei, rp, ce, eid, E);

    // conv 1 in x-space (64 B gather rows), then fused h1+y2 projection
    k_dx<<<gNF, nT, 0, stream>>>(x, dis, dx, N * FNODE);
    k_pull1x<<<g16, nT, 0, stream>>>(dx, rp, ce, dis, u, N);
    k_h1y2<<<gNode, nT, 0, stream>>>(u, W1, b1, W2, dis, y2, N);

    // conv 2: pull y2, emit h2 as hi/lo bf16 planes
    k_pull2<<<gNode, nT, 0, stream>>>(y2, rp, ce, dis, b2, (__bf16*)hpf, N);

    // edge MLP (MFMA, split-bf16, CSR-ordered for dst locality)
    k_edge_mlp<<<gMLP, nT, 0, stream>>>((const __bf16*)hpf, ce, eid, ea, mb1, mb2,
                                        mW3, mb3, q, E);
}